// Round 4
// baseline (294.004 us; speedup 1.0000x reference)
//
#include <hip/hip_runtime.h>
#include <hip/hip_fp16.h>

typedef unsigned int uint32;

#define B_ 16
#define N_ 400
#define D_ 256
#define H_ 8
#define DH_ 32
#define NW_ 4

#if __has_builtin(__builtin_amdgcn_exp2f)
#define EXP2(x) __builtin_amdgcn_exp2f(x)
#else
#define EXP2(x) exp2f(x)
#endif

// log2(e)/sqrt(32): exp(|qk/sqrt(32) * w|) == exp2(|qk*SCL * w|)
#define QK_SCL 0.2550348f

using bf16x8 = __attribute__((ext_vector_type(8))) short;
using f16x8  = __attribute__((ext_vector_type(8))) _Float16;
using f32x4  = __attribute__((ext_vector_type(4))) float;

__device__ __forceinline__ ushort f2b(float f) {
  uint32 u = __float_as_uint(f);
  uint32 r = (u + 0x7fffu + ((u >> 16) & 1u)) >> 16;
  return (ushort)r;
}
__device__ __forceinline__ float b2f(ushort u) {
  return __uint_as_float(((uint32)u) << 16);
}

// ---------------------------------------------------------------------------
// Convert fp32 inputs -> bf16 scratch copies (x + 6 weight matrices)
// ---------------------------------------------------------------------------
__global__ __launch_bounds__(256) void convert_kernel(
    const float* __restrict__ x,  const float* __restrict__ wq,
    const float* __restrict__ wk, const float* __restrict__ wv,
    const float* __restrict__ wo, const float* __restrict__ w1,
    const float* __restrict__ w2,
    ushort* __restrict__ xb,  ushort* __restrict__ wqb,
    ushort* __restrict__ wkb, ushort* __restrict__ wvb,
    ushort* __restrict__ wob, ushort* __restrict__ w1b,
    ushort* __restrict__ w2b) {
  int gid = blockIdx.x * 256 + threadIdx.x;   // unit = 4 floats
  const float* src; ushort* dst;
  if      (gid < 409600) { src = x;  dst = xb;  }
  else if ((gid -= 409600) < 16384) { src = wq; dst = wqb; }
  else if ((gid -= 16384) < 16384)  { src = wk; dst = wkb; }
  else if ((gid -= 16384) < 16384)  { src = wv; dst = wvb; }
  else if ((gid -= 16384) < 16384)  { src = wo; dst = wob; }
  else if ((gid -= 16384) < 65536)  { src = w1; dst = w1b; }
  else { gid -= 65536; src = w2; dst = w2b; }
  float4 f = ((const float4*)src)[gid];
  ushort4 u;
  u.x = f2b(f.x); u.y = f2b(f.y); u.z = f2b(f.z); u.w = f2b(f.w);
  *(ushort4*)&dst[(size_t)gid * 4] = u;
}

// ---------------------------------------------------------------------------
// Fused QKV GEMM: one launch, z picks {q,k,v}. 64x64 MFMA core, dbuf LDS.
// q -> fp16 HEAD-MAJOR [b][h][m][32], pre-scaled by QK_SCL.
// k -> fp16 HEAD-MAJOR [b][h][m][32].
// v -> fp16 TRANSPOSED vt[b][d][m] (stride N_=400); d = h*32+dh.
// ---------------------------------------------------------------------------
__global__ __launch_bounds__(256) void qkv_gemm(
    const ushort* __restrict__ xb, const ushort* __restrict__ wq,
    const ushort* __restrict__ wk, const ushort* __restrict__ wv,
    const float* __restrict__ bq, const float* __restrict__ bk,
    const float* __restrict__ bv,
    _Float16* __restrict__ qh, _Float16* __restrict__ kh,
    _Float16* __restrict__ vt) {
  __shared__ __align__(16) ushort As[2][64 * 40];
  __shared__ __align__(16) ushort Ws[2][64 * 40];
  int z = blockIdx.z;
  const ushort* W = (z == 0) ? wq : (z == 1) ? wk : wv;
  const float* bias = (z == 0) ? bq : (z == 1) ? bk : bv;

  int t = threadIdx.x;
  int l = t & 63, w = t >> 6;
  int n0 = blockIdx.x * 64, m0 = blockIdx.y * 64;
  int srow = t >> 2, sc = (t & 3) * 8;
  int lrow = l & 15, lk = (l >> 4) * 8;

  const uint4* ag = (const uint4*)&xb[(size_t)(m0 + srow) * 256 + sc];
  const uint4* wg = (const uint4*)&W[(size_t)(n0 + srow) * 256 + sc];
  uint4 ar = ag[0], wr = wg[0];

  f32x4 acc[4];
#pragma unroll
  for (int nt = 0; nt < 4; nt++) acc[nt] = {0.f, 0.f, 0.f, 0.f};

  for (int kk = 0; kk < 8; kk++) {
    int cur = kk & 1;
    *(uint4*)&As[cur][srow * 40 + sc] = ar;
    *(uint4*)&Ws[cur][srow * 40 + sc] = wr;
    if (kk + 1 < 8) { ar = ag[(kk + 1) * 4]; wr = wg[(kk + 1) * 4]; }
    __syncthreads();
    bf16x8 af = *(const bf16x8*)&As[cur][(16 * w + lrow) * 40 + lk];
#pragma unroll
    for (int nt = 0; nt < 4; nt++) {
      bf16x8 bf = *(const bf16x8*)&Ws[cur][(nt * 16 + lrow) * 40 + lk];
      acc[nt] = __builtin_amdgcn_mfma_f32_16x16x32_bf16(af, bf, acc[nt], 0, 0, 0);
    }
  }

  int mb = m0 + 16 * w + (l >> 4) * 4;  // multiple of 4 -> never crosses b*400
  int bb = mb / 400;
  int mi = mb - bb * 400;
#pragma unroll
  for (int nt = 0; nt < 4; nt++) {
    int n = n0 + nt * 16 + lrow;
    float bvv = bias[n];
    if (z < 2) {
      _Float16* out = z ? kh : qh;
      float scl = z ? 1.f : QK_SCL;
      int hh = n >> 5, dd = n & 31;
      _Float16* dst = out + (((size_t)(bb * 8 + hh)) * 400 + mi) * 32 + dd;
#pragma unroll
      for (int r = 0; r < 4; r++)
        dst[(size_t)r * 32] = (_Float16)((acc[nt][r] + bvv) * scl);
    } else {
      _Float16 h4[4];
#pragma unroll
      for (int r = 0; r < 4; r++) h4[r] = (_Float16)(acc[nt][r] + bvv);
      *(uint2*)&vt[((size_t)bb * 256 + n) * 400 + mi] = *(uint2*)h4;
    }
  }
}

// ---------------------------------------------------------------------------
// Fused attention v3 (unchanged from round 3): block = (b, head, 16 q-rows).
// ---------------------------------------------------------------------------
#define SP 416  // S row pitch in halves (832 B, 16B-aligned); 13 chunks of 32

__global__ __launch_bounds__(256) void attn_kernel(
    const _Float16* __restrict__ qh, const _Float16* __restrict__ kh,
    const _Float16* __restrict__ vt, const float* __restrict__ aw,
    float* __restrict__ scores, ushort* __restrict__ attnb) {
  __shared__ __align__(16) char smem[16 * SP * 2 + 256];
  __half* S = (__half*)smem;               // [16][SP] fp16
  float* zin = (float*)(smem + 16 * SP * 2);  // [4i][16n]

  int id = blockIdx.x;
  int c = ((id >> 6) << 3) | (id & 7);  // 0..399: (b, n-tile) combo
  int hh = (id >> 3) & 7;
  int b = c / 25;
  int n0 = (c - b * 25) * 16;

  int t = threadIdx.x;
  int w = t >> 6, l = t & 63;
  int lq = l >> 4, lr = l & 15;

  // ---- P1: S = (Q*scl) @ K^T ----
  {
    const _Float16* qbase = qh + (((size_t)(b * 8 + hh)) * 400 + n0) * 32;
    const _Float16* kbase = kh + ((size_t)(b * 8 + hh)) * 400 * 32;
    f16x8 af = *(const f16x8*)(qbase + lr * 32 + lq * 8);
    for (int mt = w; mt < 25; mt += 4) {
      f16x8 bf = *(const f16x8*)(kbase + (size_t)(mt * 16 + lr) * 32 + lq * 8);
      f32x4 cc = {0.f, 0.f, 0.f, 0.f};
      cc = __builtin_amdgcn_mfma_f32_16x16x32_f16(af, bf, cc, 0, 0, 0);
#pragma unroll
      for (int r = 0; r < 4; r++)
        S[(lq * 4 + r) * SP + mt * 16 + lr] = __float2half(cc[r]);
    }
  }
  __syncthreads();

  // ---- P2: Z (4 threads per (i,n) row) ----
  {
    int r = t >> 2, p = t & 3;
    int i = r >> 4, n = r & 15;
    const float* wrow = aw + (((size_t)(b * 4 + i)) * 400 + n0 + n) * 400;
    const __half* srow = S + n * SP;
    float z = 0.f;
    for (int m = p * 4; m < 400; m += 16) {
      float4 wv = *(const float4*)(wrow + m);
      float2 f0 = __half22float2(*(const __half2*)(srow + m));
      float2 f1 = __half22float2(*(const __half2*)(srow + m + 2));
      z += EXP2(fabsf(f0.x * wv.x)) + EXP2(fabsf(f0.y * wv.y)) +
           EXP2(fabsf(f1.x * wv.z)) + EXP2(fabsf(f1.y * wv.w));
    }
    z += __shfl_xor(z, 1);
    z += __shfl_xor(z, 2);
    if (p == 0) zin[r] = 0.25f / (z + 1e-10f);  // folds the /NW
  }
  __syncthreads();

  // ---- P3a: scores; overwrite S in place with normalized fp16 scores ----
  {
    int n = t >> 4, p = t & 15;
    float zz[4] = {zin[n], zin[16 + n], zin[32 + n], zin[48 + n]};
    __half* srow = S + n * SP;
    const float* awn = aw + (((size_t)(b * 4)) * 400 + n0 + n) * 400;
    float* scout = scores + (((size_t)(b * 8 + hh)) * 400 + n0 + n) * 400;
    for (int m = p * 4; m < 448; m += 64) {
      if (m < 400) {
        float2 f0 = __half22float2(*(const __half2*)(srow + m));
        float2 f1 = __half22float2(*(const __half2*)(srow + m + 2));
        float q0 = f0.x, q1 = f0.y, q2 = f1.x, q3 = f1.y;
        float s0 = 0.f, s1 = 0.f, s2 = 0.f, s3 = 0.f;
#pragma unroll
        for (int i = 0; i < 4; i++) {
          float4 wv = *(const float4*)(awn + (size_t)i * 160000 + m);
          float t0 = q0 * wv.x; s0 += copysignf(EXP2(fabsf(t0)) * zz[i], t0);
          float t1 = q1 * wv.y; s1 += copysignf(EXP2(fabsf(t1)) * zz[i], t1);
          float t2 = q2 * wv.z; s2 += copysignf(EXP2(fabsf(t2)) * zz[i], t2);
          float t3 = q3 * wv.w; s3 += copysignf(EXP2(fabsf(t3)) * zz[i], t3);
        }
        float4 o = {s0, s1, s2, s3};
        *(float4*)(scout + m) = o;
        __half h4[4] = {__float2half(s0), __float2half(s1),
                        __float2half(s2), __float2half(s3)};
        *(uint2*)(srow + m) = *(uint2*)h4;
      } else if (m < 416) {
        uint2 zero = {0u, 0u};
        *(uint2*)(srow + m) = zero;  // zero-pad cols 400..415 for PV chunks
      }
    }
  }
  __syncthreads();

  // ---- P3b: O = S @ V (13 chunks of 32 m, split across waves) ----
  const _Float16* vbase = vt + (((size_t)b) * 256 + hh * 32) * 400;
  f32x4 a0 = {0.f, 0.f, 0.f, 0.f}, a1 = {0.f, 0.f, 0.f, 0.f};
  const _Float16* Sh = (const _Float16*)S;
  for (int c2 = w; c2 < 13; c2 += 4) {
    f16x8 sf = *(const f16x8*)(Sh + lr * SP + c2 * 32 + lq * 8);
    f16x8 v0 = *(const f16x8*)(vbase + (size_t)lr * 400 + c2 * 32 + lq * 8);
    f16x8 v1 = *(const f16x8*)(vbase + (size_t)(16 + lr) * 400 + c2 * 32 + lq * 8);
    a0 = __builtin_amdgcn_mfma_f32_16x16x32_f16(sf, v0, a0, 0, 0, 0);
    a1 = __builtin_amdgcn_mfma_f32_16x16x32_f16(sf, v1, a1, 0, 0, 0);
  }
  __syncthreads();  // all S reads done before overwriting as float scratch
  float* Of = (float*)smem;  // [4w][16n][32d]
#pragma unroll
  for (int r = 0; r < 4; r++) {
    Of[(w * 16 + lq * 4 + r) * 32 + lr] = a0[r];
    Of[(w * 16 + lq * 4 + r) * 32 + 16 + lr] = a1[r];
  }
  __syncthreads();
  for (int o = t; o < 512; o += 256) {
    int n = o >> 5, d = o & 31;
    float s = Of[n * 32 + d] + Of[512 + n * 32 + d] +
              Of[1024 + n * 32 + d] + Of[1536 + n * 32 + d];
    attnb[((size_t)(b * 400 + n0 + n)) * 256 + hh * 32 + d] = f2b(s);
  }
}

// ---------------------------------------------------------------------------
// Fused tail: per block = 16 rows. Wo(+x resid) -> LN1 -> FFN1(relu) ->
// FFN2(+h resid) -> LN2 -> y. 512 threads (8 waves). Weights read as MFMA
// B-fragments straight from global (L2-resident, 1 KB coalesced per instr);
// only activations staged in LDS. LayerNorm via shfl_xor(16-group) + LDS.
// LDS: bufA 8.7 KB (attn rows, then h bf16) + relu 33.3 KB + ln 1 KB = 43 KB.
// ---------------------------------------------------------------------------
#define HP 272   // bufA row pitch (halves): 544 B, 16B-aligned, stride 136 dw
#define RP 1040  // relu row pitch (halves): 2080 B, stride 520 dw

__global__ __launch_bounds__(512, 2) void tail_kernel(
    const ushort* __restrict__ attnb, const ushort* __restrict__ wob,
    const float* __restrict__ bo, const float* __restrict__ x,
    const float* __restrict__ g1, const float* __restrict__ be1,
    const ushort* __restrict__ w1b, const float* __restrict__ b1,
    const ushort* __restrict__ w2b, const float* __restrict__ b2,
    const float* __restrict__ g2, const float* __restrict__ be2,
    float* __restrict__ yout) {
  __shared__ __align__(16) ushort bufA[16 * HP];  // attn rows -> h bf16
  __shared__ __align__(16) ushort relu[16 * RP];  // ffn1 relu out bf16
  __shared__ float lnS[16 * 8], lnQ[16 * 8];

  int m0 = blockIdx.x * 16;
  int t = threadIdx.x, w = t >> 6, l = t & 63;
  int lr = l & 15, lq = l >> 4;
  int row4 = lq * 4;  // C/D layout: row = lq*4 + r, col = lr

  // ---- load 16 attn rows (bf16) into LDS ----
  {
    int row = t >> 5, c = (t & 31) * 8;
    *(uint4*)&bufA[row * HP + c] =
        *(const uint4*)&attnb[(size_t)(m0 + row) * 256 + c];
  }
  __syncthreads();

  // ---- Wo stage: 2 n-tiles per wave (cols w*32 .. w*32+31) ----
  f32x4 acc[2];
  acc[0] = {0.f, 0.f, 0.f, 0.f}; acc[1] = {0.f, 0.f, 0.f, 0.f};
  for (int ks = 0; ks < 8; ks++) {
    bf16x8 af = *(const bf16x8*)&bufA[lr * HP + ks * 32 + lq * 8];
#pragma unroll
    for (int nt = 0; nt < 2; nt++) {
      bf16x8 bf = *(const bf16x8*)&wob[(size_t)(w * 32 + nt * 16 + lr) * 256 +
                                       ks * 32 + lq * 8];
      acc[nt] = __builtin_amdgcn_mfma_f32_16x16x32_bf16(af, bf, acc[nt], 0, 0, 0);
    }
  }
  // epilogue: + bo + x resid; LN1 partials
  float vals[2][4];
  float rs[4] = {0.f, 0.f, 0.f, 0.f}, rq[4] = {0.f, 0.f, 0.f, 0.f};
#pragma unroll
  for (int nt = 0; nt < 2; nt++) {
    int n = w * 32 + nt * 16 + lr;
    float bon = bo[n];
#pragma unroll
    for (int r = 0; r < 4; r++) {
      float v = acc[nt][r] + bon + x[(size_t)(m0 + row4 + r) * 256 + n];
      vals[nt][r] = v;
      rs[r] += v; rq[r] += v * v;
    }
  }
#pragma unroll
  for (int r = 0; r < 4; r++) {
#pragma unroll
    for (int o = 1; o < 16; o <<= 1) {
      rs[r] += __shfl_xor(rs[r], o);
      rq[r] += __shfl_xor(rq[r], o);
    }
  }
  if (lr == 0) {
#pragma unroll
    for (int r = 0; r < 4; r++) {
      lnS[(row4 + r) * 8 + w] = rs[r];
      lnQ[(row4 + r) * 8 + w] = rq[r];
    }
  }
  __syncthreads();
  {
    float mean[4], rsig[4];
#pragma unroll
    for (int r = 0; r < 4; r++) {
      int m = row4 + r;
      float s = 0.f, q = 0.f;
#pragma unroll
      for (int j = 0; j < 8; j++) { s += lnS[m * 8 + j]; q += lnQ[m * 8 + j]; }
      float mu = s * (1.f / 256.f);
      float va = q * (1.f / 256.f) - mu * mu;
      mean[r] = mu; rsig[r] = rsqrtf(va + 1e-5f);
    }
#pragma unroll
    for (int nt = 0; nt < 2; nt++) {
      int n = w * 32 + nt * 16 + lr;
      float g = g1[n], be = be1[n];
#pragma unroll
      for (int r = 0; r < 4; r++) {
        float h = (vals[nt][r] - mean[r]) * rsig[r] * g + be;
        bufA[(row4 + r) * HP + n] = f2b(h);
      }
    }
  }
  __syncthreads();

  // ---- FFN1: 8 n-tiles per wave (cols w*128 .. w*128+127), relu -> LDS ----
  {
    f32x4 a1[8];
#pragma unroll
    for (int nt = 0; nt < 8; nt++) a1[nt] = {0.f, 0.f, 0.f, 0.f};
    for (int ks = 0; ks < 8; ks++) {
      bf16x8 af = *(const bf16x8*)&bufA[lr * HP + ks * 32 + lq * 8];
#pragma unroll
      for (int nt = 0; nt < 8; nt++) {
        bf16x8 bf = *(const bf16x8*)&w1b[(size_t)(w * 128 + nt * 16 + lr) * 256 +
                                         ks * 32 + lq * 8];
        a1[nt] = __builtin_amdgcn_mfma_f32_16x16x32_bf16(af, bf, a1[nt], 0, 0, 0);
      }
    }
#pragma unroll
    for (int nt = 0; nt < 8; nt++) {
      int n = w * 128 + nt * 16 + lr;
      float bn = b1[n];
#pragma unroll
      for (int r = 0; r < 4; r++) {
        float v = fmaxf(a1[nt][r] + bn, 0.f);
        relu[(row4 + r) * RP + n] = f2b(v);
      }
    }
  }
  __syncthreads();

  // ---- FFN2: 2 n-tiles per wave, K=1024 from relu LDS ----
  f32x4 a2[2];
  a2[0] = {0.f, 0.f, 0.f, 0.f}; a2[1] = {0.f, 0.f, 0.f, 0.f};
  for (int ks = 0; ks < 32; ks++) {
    bf16x8 af = *(const bf16x8*)&relu[lr * RP + ks * 32 + lq * 8];
#pragma unroll
    for (int nt = 0; nt < 2; nt++) {
      bf16x8 bf = *(const bf16x8*)&w2b[(size_t)(w * 32 + nt * 16 + lr) * 1024 +
                                       ks * 32 + lq * 8];
      a2[nt] = __builtin_amdgcn_mfma_f32_16x16x32_bf16(af, bf, a2[nt], 0, 0, 0);
    }
  }
  // epilogue: + b2 + h resid; LN2
  float vals2[2][4];
  float rs2[4] = {0.f, 0.f, 0.f, 0.f}, rq2[4] = {0.f, 0.f, 0.f, 0.f};
#pragma unroll
  for (int nt = 0; nt < 2; nt++) {
    int n = w * 32 + nt * 16 + lr;
    float bn = b2[n];
#pragma unroll
    for (int r = 0; r < 4; r++) {
      float v = a2[nt][r] + bn + b2f(bufA[(row4 + r) * HP + n]);
      vals2[nt][r] = v;
      rs2[r] += v; rq2[r] += v * v;
    }
  }
#pragma unroll
  for (int r = 0; r < 4; r++) {
#pragma unroll
    for (int o = 1; o < 16; o <<= 1) {
      rs2[r] += __shfl_xor(rs2[r], o);
      rq2[r] += __shfl_xor(rq2[r], o);
    }
  }
  if (lr == 0) {
#pragma unroll
    for (int r = 0; r < 4; r++) {
      lnS[(row4 + r) * 8 + w] = rs2[r];
      lnQ[(row4 + r) * 8 + w] = rq2[r];
    }
  }
  __syncthreads();
  {
    float mean[4], rsig[4];
#pragma unroll
    for (int r = 0; r < 4; r++) {
      int m = row4 + r;
      float s = 0.f, q = 0.f;
#pragma unroll
      for (int j = 0; j < 8; j++) { s += lnS[m * 8 + j]; q += lnQ[m * 8 + j]; }
      float mu = s * (1.f / 256.f);
      float va = q * (1.f / 256.f) - mu * mu;
      mean[r] = mu; rsig[r] = rsqrtf(va + 1e-5f);
    }
#pragma unroll
    for (int nt = 0; nt < 2; nt++) {
      int n = w * 32 + nt * 16 + lr;
      float g = g2[n], be = be2[n];
#pragma unroll
      for (int r = 0; r < 4; r++) {
        float y = (vals2[nt][r] - mean[r]) * rsig[r] * g + be;
        yout[(size_t)(m0 + row4 + r) * 256 + n] = y;
      }
    }
  }
}

// ---------------------------------------------------------------------------
extern "C" void kernel_launch(void* const* d_in, const int* in_sizes, int n_in,
                              void* d_out, int out_size, void* d_ws,
                              size_t ws_size, hipStream_t stream) {
  const float* x   = (const float*)d_in[0];
  const float* aw  = (const float*)d_in[1];
  const float* Wq  = (const float*)d_in[2];
  const float* bq  = (const float*)d_in[3];
  const float* Wk  = (const float*)d_in[4];
  const float* bk  = (const float*)d_in[5];
  const float* Wv  = (const float*)d_in[6];
  const float* bv  = (const float*)d_in[7];
  const float* Wo  = (const float*)d_in[8];
  const float* bo  = (const float*)d_in[9];
  const float* g1  = (const float*)d_in[10];
  const float* be1 = (const float*)d_in[11];
  const float* W1  = (const float*)d_in[12];
  const float* b1  = (const float*)d_in[13];
  const float* W2  = (const float*)d_in[14];
  const float* b2  = (const float*)d_in[15];
  const float* g2  = (const float*)d_in[16];
  const float* be2 = (const float*)d_in[17];

  if (ws_size < 34340864) return;  // scratch layout requirement

  char* ws = (char*)d_ws;
  ushort*   xb    = (ushort*)(ws + 0);          // 3,276,800
  ushort*   wqb   = (ushort*)(ws + 3276800);    //   131,072
  ushort*   wkb   = (ushort*)(ws + 3407872);
  ushort*   wvb   = (ushort*)(ws + 3538944);
  ushort*   wob   = (ushort*)(ws + 3670016);
  ushort*   w1b   = (ushort*)(ws + 3801088);    //   524,288
  ushort*   w2b   = (ushort*)(ws + 4325376);    //   524,288
  _Float16* qhb   = (_Float16*)(ws + 4849664);  // 3,276,800  [b][h][m][32]*scl
  _Float16* khb   = (_Float16*)(ws + 8126464);  //            [b][h][m][32]
  _Float16* vtb   = (_Float16*)(ws + 11403264); //            [b][d][m]
  ushort*   attnb = (ushort*)(ws + 14680064);   // 3,276,800

  float* yout   = (float*)d_out;
  float* scores = yout + 1638400;

  convert_kernel<<<2368, 256, 0, stream>>>(x, Wq, Wk, Wv, Wo, W1, W2,
                                           xb, wqb, wkb, wvb, wob, w1b, w2b);
  qkv_gemm<<<dim3(4, 100, 3), 256, 0, stream>>>(
      xb, wqb, wkb, wvb, bq, bk, bv, qhb, khb, vtb);
  attn_kernel<<<3200, 256, 0, stream>>>(qhb, khb, vtb, aw, scores, attnb);
  tail_kernel<<<400, 512, 0, stream>>>(attnb, wob, bo, x, g1, be1,
                                       w1b, b1, w2b, b2, g2, be2, yout);
}